// Round 11
// baseline (334.296 us; speedup 1.0000x reference)
//
#include <hip/hip_runtime.h>
#include <math.h>

#define NGRAPH 128
#define KTOP 30
#define LATENT 193
#define HID 64

typedef unsigned short u16;

// ---------------- zero edeg ----------------
__global__ void k_zero(int* edeg, int n) {
    int i = blockIdx.x * blockDim.x + threadIdx.x;
    if (i < n) edeg[i] = 0;
}

// ---------------- shared GEMM tile: 64x64 out, BK=32, k-major LDS ------------
template <bool SCALE>
__device__ __forceinline__ void gemm_tile(const float* __restrict__ A,
                                          const float* __restrict__ W,
                                          const float* __restrict__ dinv,
                                          float* __restrict__ Hs,
                                          int M, int K, int br,
                                          float (*As)[68], float (*Bs)[68]) {
    int tid = threadIdx.x;
    int tx = tid & 15, ty = tid >> 4;
    int kA = (tid & 7) * 4;
    int rA = tid >> 3;
    int kB = tid >> 3;
    int cB = (tid & 7) * 8;
    float c[4][4] = {};
    for (int k0 = 0; k0 < K; k0 += 32) {
#pragma unroll
        for (int it = 0; it < 2; ++it) {
            int row = it * 32 + rA;
            int grow = br + row;
            float4 v = make_float4(0.f, 0.f, 0.f, 0.f);
            if (grow < M) v = *(const float4*)(A + (size_t)grow * K + k0 + kA);
            As[kA + 0][row] = v.x;
            As[kA + 1][row] = v.y;
            As[kA + 2][row] = v.z;
            As[kA + 3][row] = v.w;
        }
        {
            const float* wp = W + (size_t)(k0 + kB) * 64 + cB;
            float4 v0 = *(const float4*)(wp);
            float4 v1 = *(const float4*)(wp + 4);
            *(float4*)&Bs[kB][cB] = v0;
            *(float4*)&Bs[kB][cB + 4] = v1;
        }
        __syncthreads();
#pragma unroll
        for (int kk = 0; kk < 32; ++kk) {
            float4 a4 = *(const float4*)&As[kk][ty * 4];
            float4 b4 = *(const float4*)&Bs[kk][tx * 4];
            c[0][0] += a4.x * b4.x; c[0][1] += a4.x * b4.y; c[0][2] += a4.x * b4.z; c[0][3] += a4.x * b4.w;
            c[1][0] += a4.y * b4.x; c[1][1] += a4.y * b4.y; c[1][2] += a4.y * b4.z; c[1][3] += a4.y * b4.w;
            c[2][0] += a4.z * b4.x; c[2][1] += a4.z * b4.y; c[2][2] += a4.z * b4.z; c[2][3] += a4.z * b4.w;
            c[3][0] += a4.w * b4.x; c[3][1] += a4.w * b4.y; c[3][2] += a4.w * b4.z; c[3][3] += a4.w * b4.w;
        }
        __syncthreads();
    }
#pragma unroll
    for (int i = 0; i < 4; i++) {
        int row = br + ty * 4 + i;
        if (row >= M) continue;
        float d = SCALE ? dinv[row] : 1.f;
        float4 o;
        o.x = c[i][0] * d; o.y = c[i][1] * d; o.z = c[i][2] * d; o.w = c[i][3] * d;
        *(float4*)(Hs + (size_t)row * HID + tx * 4) = o;
    }
}

// ---- K1: fused layer-1 GEMM (raw) + edge hist/rank (4 edges/thr) + starts ----
__global__ __launch_bounds__(256) void k_gemm_hist(
        const float* __restrict__ A, const float* __restrict__ W,
        float* __restrict__ Hs, int M, int K, int NG,
        const int* __restrict__ dst, const int* __restrict__ batch,
        int* edeg, u16* __restrict__ rank, int* starts,
        int E, int n, int NH) {
    __shared__ float As[32][68];
    __shared__ float Bs[32][68];
    int bid = blockIdx.x;
    if ((bid & 1) == 0) {
        int gid = bid >> 1;
        if (gid >= NG) return;
        gemm_tile<false>(A, W, nullptr, Hs, M, K, gid * 64, As, Bs);
    } else {
        int fid = bid >> 1;
        if (fid >= NH) return;
        int t = threadIdx.x;
        int gi = fid * 256 + t;
        if (gi < n) {
            int b = batch[gi];
            if (gi == 0) {
                for (int g = 0; g <= b; g++) starts[g] = 0;
            } else {
                int pb = batch[gi - 1];
                for (int g = pb + 1; g <= b; g++) starts[g] = gi;
            }
            if (gi == n - 1) {
                for (int g = b + 1; g <= NGRAPH; g++) starts[g] = n;
            }
        }
        int base = fid * 1024;
#pragma unroll
        for (int k = 0; k < 4; k++) {
            int e = base + k * 256 + t;
            if (e < E) {
                int d = dst[e];
                rank[e] = (u16)atomicAdd(&edeg[d], 1);
            }
        }
    }
}

// ---------------- scan stage 1 ----------------
__global__ void k_scan1(const int* __restrict__ edeg, int* offs, int* bsum,
                        float* dinv, int n) {
    __shared__ int s[256];
    int t = threadIdx.x;
    int gi = blockIdx.x * 256 + t;
    int v = (gi < n) ? edeg[gi] : 0;
    if (gi < n) dinv[gi] = rsqrtf((float)(v + 1));
    s[t] = v;
    __syncthreads();
    for (int o = 1; o < 256; o <<= 1) {
        int add = (t >= o) ? s[t - o] : 0;
        __syncthreads();
        s[t] += add;
        __syncthreads();
    }
    if (gi < n) offs[gi] = s[t] - v;
    if (t == 255) bsum[blockIdx.x] = s[255];
}

// ---------------- scan stage 2+3 fused ----------------
__global__ void k_scan23(int* offs, const int* __restrict__ bsum,
                         int n, int E, int nb) {
    __shared__ int s[256];
    int t = threadIdx.x;
    int bid = blockIdx.x;
    int v = (t < nb) ? bsum[t] : 0;
    s[t] = v;
    __syncthreads();
    for (int o = 1; o < 256; o <<= 1) {
        int add = (t >= o) ? s[t - o] : 0;
        __syncthreads();
        s[t] += add;
        __syncthreads();
    }
    int boffv = (bid == 0) ? 0 : s[bid - 1];
    int gi = bid * 256 + t;
    if (gi < n) offs[gi] += boffv;
    if (gi == 0) offs[n] = E;
}

// ---------------- CSR fill (no atomics) ----------------
__global__ __launch_bounds__(256) void k_fill(const int* __restrict__ src,
                                              const int* __restrict__ dst,
                                              const u16* __restrict__ rank,
                                              const int* __restrict__ offs,
                                              u16* __restrict__ csr, int E) {
    int t = blockIdx.x * 256 + threadIdx.x;
    int e0 = t * 4;
    if (e0 + 4 <= E) {
        int4 s4 = *(const int4*)(src + e0);
        int4 d4 = *(const int4*)(dst + e0);
        uint2 rv = *(const uint2*)(rank + e0);
        csr[offs[d4.x] + (rv.x & 0xffff)] = (u16)s4.x;
        csr[offs[d4.y] + (rv.x >> 16)]    = (u16)s4.y;
        csr[offs[d4.z] + (rv.y & 0xffff)] = (u16)s4.z;
        csr[offs[d4.w] + (rv.y >> 16)]    = (u16)s4.w;
    } else {
        for (int e = e0; e < E; e++)
            csr[offs[dst[e]] + rank[e]] = (u16)src[e];
    }
}

// ---------------- plain GEMM (layers 2,3): Hs = (A @ W) * dinv[row] ----------
__global__ __launch_bounds__(256) void k_gemm(const float* __restrict__ A,
                                              const float* __restrict__ W,
                                              const float* __restrict__ dinv,
                                              float* __restrict__ Hs,
                                              int M, int K) {
    __shared__ float As[32][68];
    __shared__ float Bs[32][68];
    gemm_tile<true>(A, W, dinv, Hs, M, K, blockIdx.x * 64, As, Bs);
}

// ------- aggregate, FEATURE-HALF pass: wave = 32 features x 2 edge slots -----
// HALF selects bytes [HALF*128, HALF*128+128) of each 256B row -> 6.4MB
// working set per pass (vs 12.8MB), raising per-XCD L2 residency.
// lane: feat = (lane&31)+HALF*32, slot = lane>>5 (edge parity).
// End: slot-combine via shfl_xor(32); slot-0 lanes write the 128B half-row.
template <bool DEFER, bool FUSE_TS, int HALF>
__global__ __launch_bounds__(256) void k_agg_half(
        const float* __restrict__ Hs, const u16* __restrict__ csr,
        const int* __restrict__ offs, const float* __restrict__ dinv,
        const float* __restrict__ b, float* __restrict__ H, int n,
        const float* __restrict__ w3, float* __restrict__ ts) {
    int wid = threadIdx.x >> 6;
    int lane = threadIdx.x & 63;
    int feat = (lane & 31) + HALF * 32;
    int slot = lane >> 5;
    int node = blockIdx.x * 4 + wid;
    if (node >= n) return;
    float d = dinv[node];
    float acc = 0.f;
    if (slot == 0) {                       // self-loop term once
        acc = Hs[(size_t)node * HID + feat];
        if (DEFER) acc *= d;
    }
    int s = offs[node], e = offs[node + 1];
    int base = s;
    // main: 8 iters x 2 edges = 16 edges per pass through
    while (base + 16 <= e) {
        float p = 0.f;
#pragma unroll
        for (int k = 0; k < 8; k++) {
            int u = csr[base + 2 * k + slot];
            float v = Hs[(size_t)u * HID + feat];
            if (DEFER) v *= dinv[u];
            p += v;
        }
        acc += p;
        base += 16;
    }
    // tail: 2 edges per iter, per-lane guarded
    for (; base < e; base += 2) {
        int pos = base + slot;
        if (pos < e) {
            int u = csr[pos];
            float v = Hs[(size_t)u * HID + feat];
            if (DEFER) v *= dinv[u];
            acc += v;
        }
    }
    // combine the two edge slots (lane l <-> l^32 hold the same feature)
    acc += __shfl_xor(acc, 32, 64);
    float h = tanhf(acc * d + b[feat]);
    if (slot == 0) H[(size_t)node * HID + feat] = h;
    if (FUSE_TS) {
        // per-half partial of ts = (sum_f h[f]*w3[f]) * d ; pass order fixes race
        float v = h * w3[feat];
        for (int o = 16; o > 0; o >>= 1) v += __shfl_down(v, o, 32);
        if (lane == 0) {
            float part = v * d;
            if (HALF == 0) ts[node] = part;
            else           ts[node] += part;
        }
    }
}

// -------- fused: layer-4 aggregate (own graph's nodes) + select + tail -------
__global__ __launch_bounds__(1024) void k_select_tail(
        const float* __restrict__ h1, const float* __restrict__ h2,
        const float* __restrict__ h3, const float* __restrict__ ts,
        const u16* __restrict__ csr, const int* __restrict__ offs,
        const float* __restrict__ dinv, const float* __restrict__ b3,
        const int* __restrict__ starts,
        const float* __restrict__ c1w, const float* __restrict__ c1b,
        const float* __restrict__ c2w, const float* __restrict__ c2b,
        const float* __restrict__ l1w, const float* __restrict__ l1b,
        const float* __restrict__ l2w, const float* __restrict__ l2b,
        float* __restrict__ out) {
    __shared__ float p[KTOP * LATENT];
    __shared__ float w1s[16 * LATENT];
    __shared__ float w2s[32 * 16 * 5];
    __shared__ float vv[2048];
    __shared__ int   pr[2048];
    __shared__ int   sel_s[KTOP];
    __shared__ float zpart[960];
    __shared__ float z1[16 * KTOP];
    __shared__ float z1p[16 * 15];
    __shared__ float flat[352];
    __shared__ float part[1024];
    __shared__ float y1[256];
    int g = blockIdx.x;
    int t = threadIdx.x;
    int s = starts[g];
    int c = starts[g + 1] - s;
    if (c > 2048) c = 2048;

    for (int i = t; i < 16 * LATENT; i += 1024) w1s[i] = c1w[i];
    for (int i = t; i < 32 * 16 * 5; i += 1024) w2s[i] = c2w[i];
    if (t < KTOP) sel_s[t] = -1;

    // ---- layer-4 aggregate for this graph's own (contiguous) nodes ----
    float bb = b3[0];
    for (int i = t; i < c; i += 1024) {
        int node = s + i;
        float acc = ts[node];
        int es = offs[node], ee = offs[node + 1];
        for (int j = es; j < ee; j++) acc += ts[csr[j]];
        vv[i] = tanhf(acc * dinv[node] + bb);
    }
    __syncthreads();

    // ---- select, 2-way j-split ----
    int chalf = c >> 1;
    for (int i2 = t; i2 < 2 * c; i2 += 1024) {
        int i = i2 >> 1, half = i2 & 1;
        float vi = vv[i];
        int j0 = half ? chalf : 0;
        int j1 = half ? c : chalf;
        int r = 0;
        for (int j = j0; j < j1; j++) {
            float vj = vv[j];
            r += (vj > vi) || (vj == vi && j < i);
        }
        pr[i2] = r;
    }
    __syncthreads();
    for (int i = t; i < c; i += 1024) {
        int r = pr[2 * i] + pr[2 * i + 1];
        if (r < KTOP) sel_s[r] = s + i;
    }
    __syncthreads();

    // ---- gather latent rows ----
    for (int i = t; i < KTOP * LATENT; i += 1024) {
        int slot = i / LATENT;
        int j = i - slot * LATENT;
        int node = sel_s[slot];
        float v = 0.f;
        if (node >= 0) {
            if (j < 64)       v = h1[(size_t)node * HID + j];
            else if (j < 128) v = h2[(size_t)node * HID + j - 64];
            else if (j < 192) v = h3[(size_t)node * HID + j - 128];
            else              v = vv[node - s];
        }
        p[i] = v;
    }
    __syncthreads();
    // conv1 193->16 + relu, 2-way K-split
    if (t < 960) {
        int to = (t < 480) ? t : t - 480;
        int half = (t < 480) ? 0 : 1;
        int ch = to / KTOP, tt = to - ch * KTOP;
        const float* wp = &w1s[ch * LATENT];
        const float* pp = &p[tt * LATENT];
        int j0 = half ? 96 : 0;
        int j1 = half ? LATENT : 96;
        float sa = 0.f;
        for (int j = j0; j < j1; j++) sa += pp[j] * wp[j];
        zpart[t] = sa;
    }
    __syncthreads();
    if (t < 480) {
        int ch = t / KTOP, tt = t - ch * KTOP;
        z1[ch * KTOP + tt] = fmaxf(zpart[t] + zpart[480 + t] + c1b[ch], 0.f);
    }
    __syncthreads();
    if (t < 16 * 15) {
        int ch = t / 15, tt = t - ch * 15;
        z1p[t] = fmaxf(z1[ch * KTOP + 2 * tt], z1[ch * KTOP + 2 * tt + 1]);
    }
    __syncthreads();
    if (t < 32 * 11) {
        int c2 = t / 11, tt = t - c2 * 11;
        float sa = c2b[c2];
        for (int c1i = 0; c1i < 16; c1i++) {
            const float* wp = &w2s[(c2 * 16 + c1i) * 5];
            const float* zp = &z1p[c1i * 15 + tt];
#pragma unroll
            for (int dt = 0; dt < 5; dt++) sa += zp[dt] * wp[dt];
        }
        flat[c2 * 11 + tt] = fmaxf(sa, 0.f);
    }
    __syncthreads();
    {
        int o = t & 255, ch = t >> 8;
        int i0 = ch * 88, i1 = i0 + 88;
        float sa = 0.f;
        for (int i = i0; i < i1; i++) sa += flat[i] * l1w[(size_t)i * 256 + o];
        part[t] = sa;
    }
    __syncthreads();
    if (t < 256)
        y1[t] = fmaxf(part[t] + part[256 + t] + part[512 + t] + part[768 + t] + l1b[t], 0.f);
    __syncthreads();
    if (t < 128) {
        int o = t >> 6, lane = t & 63;
        float sa = 0.f;
        for (int i = lane; i < 256; i += 64) sa += y1[i] * l2w[(size_t)i * 2 + o];
        for (int off = 32; off > 0; off >>= 1) sa += __shfl_down(sa, off, 64);
        if (lane == 0) out[g * 2 + o] = sa + l2b[o];
    }
}

// ---------------- launch ----------------
static inline char* align256(char* p) {
    return (char*)(((uintptr_t)p + 255) & ~(uintptr_t)255);
}

extern "C" void kernel_launch(void* const* d_in, const int* in_sizes, int n_in,
                              void* d_out, int out_size, void* d_ws, size_t ws_size,
                              hipStream_t stream) {
    const float* x     = (const float*)d_in[0];
    const int*  eidx   = (const int*)d_in[1];
    const int*  batch  = (const int*)d_in[2];
    const float* w0    = (const float*)d_in[3];
    const float* b0    = (const float*)d_in[4];
    const float* w1    = (const float*)d_in[5];
    const float* b1    = (const float*)d_in[6];
    const float* w2    = (const float*)d_in[7];
    const float* b2    = (const float*)d_in[8];
    const float* w3    = (const float*)d_in[9];
    const float* b3    = (const float*)d_in[10];
    const float* c1w   = (const float*)d_in[11];
    const float* c1b   = (const float*)d_in[12];
    const float* c2w   = (const float*)d_in[13];
    const float* c2b   = (const float*)d_in[14];
    const float* l1w   = (const float*)d_in[15];
    const float* l1b   = (const float*)d_in[16];
    const float* l2w   = (const float*)d_in[17];
    const float* l2b   = (const float*)d_in[18];

    int N = in_sizes[2];              // 50000 nodes
    int E = in_sizes[1] / 2;          // 800000 edges
    int K0 = in_sizes[0] / N;         // 128 input feats
    const int* esrc = eidx;
    const int* edst = eidx + E;

    char* w = (char*)d_ws;
    float* dinv  = (float*)w;             w = align256(w + (size_t)N * 4);
    int*   edeg  = (int*)w;               w = align256(w + (size_t)N * 4);
    int*   offs  = (int*)w;               w = align256(w + (size_t)(N + 1) * 4);
    int*   bsum  = (int*)w;               w = align256(w + 1024);
    float* ts    = (float*)w;             w = align256(w + (size_t)N * 4);
    int* starts  = (int*)w;               w = align256(w + (NGRAPH + 1) * 4);
    u16* rank    = (u16*)w;               w = align256(w + (size_t)E * 2);
    u16* csr     = (u16*)w;               w = align256(w + (size_t)E * 2);
    float* Hs    = (float*)w;             w = align256(w + (size_t)N * HID * 4);
    float* h1    = (float*)w;             w = align256(w + (size_t)N * HID * 4);
    float* h2    = (float*)w;             w = align256(w + (size_t)N * HID * 4);
    float* h3    = (float*)w;             w = align256(w + (size_t)N * HID * 4);

    int nb = (N + 255) / 256;             // 196
    int NG = (N + 63) / 64;               // 782
    int NH = (E + 1023) / 1024;           // 782 (4 edges per thread)
    int agg_grid = (N + 3) / 4;

    // zero degree array
    k_zero<<<nb, 256, 0, stream>>>(edeg, N);

    // K1: layer-1 GEMM (raw) || edge histogram+rank || graph starts
    int g1 = 2 * (NG > NH ? NG : NH);
    k_gemm_hist<<<g1, 256, 0, stream>>>(x, w0, Hs, N, K0, NG,
                                        edst, batch, edeg, rank, starts, E, N, NH);

    // CSR offsets + dinv
    k_scan1<<<nb, 256, 0, stream>>>(edeg, offs, bsum, dinv, N);
    k_scan23<<<nb, 256, 0, stream>>>(offs, bsum, N, E, nb);

    // CSR fill (no atomics)
    k_fill<<<(E / 4 + 255) / 256 + 1, 256, 0, stream>>>(esrc, edst, rank, offs, csr, E);

    // layer 1 aggregate (deferred dinv), feature-half passes -> h1
    k_agg_half<true, false, 0><<<agg_grid, 256, 0, stream>>>(Hs, csr, offs, dinv, b0, h1, N, nullptr, nullptr);
    k_agg_half<true, false, 1><<<agg_grid, 256, 0, stream>>>(Hs, csr, offs, dinv, b0, h1, N, nullptr, nullptr);
    // layer 2
    k_gemm<<<NG, 256, 0, stream>>>(h1, w1, dinv, Hs, N, HID);
    k_agg_half<false, false, 0><<<agg_grid, 256, 0, stream>>>(Hs, csr, offs, dinv, b1, h2, N, nullptr, nullptr);
    k_agg_half<false, false, 1><<<agg_grid, 256, 0, stream>>>(Hs, csr, offs, dinv, b1, h2, N, nullptr, nullptr);
    // layer 3 (+ fused layer-4 prescaled GEMV -> ts, per-half partials)
    k_gemm<<<NG, 256, 0, stream>>>(h2, w2, dinv, Hs, N, HID);
    k_agg_half<false, true, 0><<<agg_grid, 256, 0, stream>>>(Hs, csr, offs, dinv, b2, h3, N, w3, ts);
    k_agg_half<false, true, 1><<<agg_grid, 256, 0, stream>>>(Hs, csr, offs, dinv, b2, h3, N, w3, ts);

    // fused layer-4 aggregate + top-30 select + tail
    k_select_tail<<<NGRAPH, 1024, 0, stream>>>(h1, h2, h3, ts, csr, offs, dinv, b3,
                                               starts,
                                               c1w, c1b, c2w, c2b,
                                               l1w, l1b, l2w, l2b,
                                               (float*)d_out);
}

// Round 12
// 303.812 us; speedup vs baseline: 1.1003x; 1.1003x over previous
//
#include <hip/hip_runtime.h>
#include <math.h>

#define NGRAPH 128
#define KTOP 30
#define LATENT 193
#define HID 64

typedef unsigned short u16;

// ---------------- zero edeg ----------------
__global__ void k_zero(int* edeg, int n) {
    int i = blockIdx.x * blockDim.x + threadIdx.x;
    if (i < n) edeg[i] = 0;
}

// ---------------- shared GEMM tile: 64x64 out, BK=32, k-major LDS ------------
template <bool SCALE>
__device__ __forceinline__ void gemm_tile(const float* __restrict__ A,
                                          const float* __restrict__ W,
                                          const float* __restrict__ dinv,
                                          float* __restrict__ Hs,
                                          int M, int K, int br,
                                          float (*As)[68], float (*Bs)[68]) {
    int tid = threadIdx.x;
    int tx = tid & 15, ty = tid >> 4;
    int kA = (tid & 7) * 4;
    int rA = tid >> 3;
    int kB = tid >> 3;
    int cB = (tid & 7) * 8;
    float c[4][4] = {};
    for (int k0 = 0; k0 < K; k0 += 32) {
#pragma unroll
        for (int it = 0; it < 2; ++it) {
            int row = it * 32 + rA;
            int grow = br + row;
            float4 v = make_float4(0.f, 0.f, 0.f, 0.f);
            if (grow < M) v = *(const float4*)(A + (size_t)grow * K + k0 + kA);
            As[kA + 0][row] = v.x;
            As[kA + 1][row] = v.y;
            As[kA + 2][row] = v.z;
            As[kA + 3][row] = v.w;
        }
        {
            const float* wp = W + (size_t)(k0 + kB) * 64 + cB;
            float4 v0 = *(const float4*)(wp);
            float4 v1 = *(const float4*)(wp + 4);
            *(float4*)&Bs[kB][cB] = v0;
            *(float4*)&Bs[kB][cB + 4] = v1;
        }
        __syncthreads();
#pragma unroll
        for (int kk = 0; kk < 32; ++kk) {
            float4 a4 = *(const float4*)&As[kk][ty * 4];
            float4 b4 = *(const float4*)&Bs[kk][tx * 4];
            c[0][0] += a4.x * b4.x; c[0][1] += a4.x * b4.y; c[0][2] += a4.x * b4.z; c[0][3] += a4.x * b4.w;
            c[1][0] += a4.y * b4.x; c[1][1] += a4.y * b4.y; c[1][2] += a4.y * b4.z; c[1][3] += a4.y * b4.w;
            c[2][0] += a4.z * b4.x; c[2][1] += a4.z * b4.y; c[2][2] += a4.z * b4.z; c[2][3] += a4.z * b4.w;
            c[3][0] += a4.w * b4.x; c[3][1] += a4.w * b4.y; c[3][2] += a4.w * b4.z; c[3][3] += a4.w * b4.w;
        }
        __syncthreads();
    }
#pragma unroll
    for (int i = 0; i < 4; i++) {
        int row = br + ty * 4 + i;
        if (row >= M) continue;
        float d = SCALE ? dinv[row] : 1.f;
        float4 o;
        o.x = c[i][0] * d; o.y = c[i][1] * d; o.z = c[i][2] * d; o.w = c[i][3] * d;
        *(float4*)(Hs + (size_t)row * HID + tx * 4) = o;
    }
}

// ---- K1: fused layer-1 GEMM (raw) + edge hist/rank (4 edges/thr) + starts ----
__global__ __launch_bounds__(256) void k_gemm_hist(
        const float* __restrict__ A, const float* __restrict__ W,
        float* __restrict__ Hs, int M, int K, int NG,
        const int* __restrict__ dst, const int* __restrict__ batch,
        int* edeg, u16* __restrict__ rank, int* starts,
        int E, int n, int NH) {
    __shared__ float As[32][68];
    __shared__ float Bs[32][68];
    int bid = blockIdx.x;
    if ((bid & 1) == 0) {
        int gid = bid >> 1;
        if (gid >= NG) return;
        gemm_tile<false>(A, W, nullptr, Hs, M, K, gid * 64, As, Bs);
    } else {
        int fid = bid >> 1;
        if (fid >= NH) return;
        int t = threadIdx.x;
        int gi = fid * 256 + t;
        if (gi < n) {
            int b = batch[gi];
            if (gi == 0) {
                for (int g = 0; g <= b; g++) starts[g] = 0;
            } else {
                int pb = batch[gi - 1];
                for (int g = pb + 1; g <= b; g++) starts[g] = gi;
            }
            if (gi == n - 1) {
                for (int g = b + 1; g <= NGRAPH; g++) starts[g] = n;
            }
        }
        int base = fid * 1024;
#pragma unroll
        for (int k = 0; k < 4; k++) {
            int e = base + k * 256 + t;
            if (e < E) {
                int d = dst[e];
                rank[e] = (u16)atomicAdd(&edeg[d], 1);
            }
        }
    }
}

// ---------------- scan stage 1 ----------------
__global__ void k_scan1(const int* __restrict__ edeg, int* offs, int* bsum,
                        float* dinv, int n) {
    __shared__ int s[256];
    int t = threadIdx.x;
    int gi = blockIdx.x * 256 + t;
    int v = (gi < n) ? edeg[gi] : 0;
    if (gi < n) dinv[gi] = rsqrtf((float)(v + 1));
    s[t] = v;
    __syncthreads();
    for (int o = 1; o < 256; o <<= 1) {
        int add = (t >= o) ? s[t - o] : 0;
        __syncthreads();
        s[t] += add;
        __syncthreads();
    }
    if (gi < n) offs[gi] = s[t] - v;
    if (t == 255) bsum[blockIdx.x] = s[255];
}

// ---------------- scan stage 2+3 fused ----------------
__global__ void k_scan23(int* offs, const int* __restrict__ bsum,
                         int n, int E, int nb) {
    __shared__ int s[256];
    int t = threadIdx.x;
    int bid = blockIdx.x;
    int v = (t < nb) ? bsum[t] : 0;
    s[t] = v;
    __syncthreads();
    for (int o = 1; o < 256; o <<= 1) {
        int add = (t >= o) ? s[t - o] : 0;
        __syncthreads();
        s[t] += add;
        __syncthreads();
    }
    int boffv = (bid == 0) ? 0 : s[bid - 1];
    int gi = bid * 256 + t;
    if (gi < n) offs[gi] += boffv;
    if (gi == 0) offs[n] = E;
}

// ---------------- CSR fill (no atomics) ----------------
__global__ __launch_bounds__(256) void k_fill(const int* __restrict__ src,
                                              const int* __restrict__ dst,
                                              const u16* __restrict__ rank,
                                              const int* __restrict__ offs,
                                              u16* __restrict__ csr, int E) {
    int t = blockIdx.x * 256 + threadIdx.x;
    int e0 = t * 4;
    if (e0 + 4 <= E) {
        int4 s4 = *(const int4*)(src + e0);
        int4 d4 = *(const int4*)(dst + e0);
        uint2 rv = *(const uint2*)(rank + e0);
        csr[offs[d4.x] + (rv.x & 0xffff)] = (u16)s4.x;
        csr[offs[d4.y] + (rv.x >> 16)]    = (u16)s4.y;
        csr[offs[d4.z] + (rv.y & 0xffff)] = (u16)s4.z;
        csr[offs[d4.w] + (rv.y >> 16)]    = (u16)s4.w;
    } else {
        for (int e = e0; e < E; e++)
            csr[offs[dst[e]] + rank[e]] = (u16)src[e];
    }
}

// ---------------- plain GEMM (layers 2,3): Hs = (A @ W) * dinv[row] ----------
__global__ __launch_bounds__(256) void k_gemm(const float* __restrict__ A,
                                              const float* __restrict__ W,
                                              const float* __restrict__ dinv,
                                              float* __restrict__ Hs,
                                              int M, int K) {
    __shared__ float As[32][68];
    __shared__ float Bs[32][68];
    gemm_tile<true>(A, W, dinv, Hs, M, K, blockIdx.x * 64, As, Bs);
}

// ------- aggregate (wave per node, R7-proven) + nontemporal row gathers ------
template <bool DEFER, bool FUSE_TS>
__global__ __launch_bounds__(256) void k_agg(const float* __restrict__ Hs,
                                             const u16* __restrict__ csr,
                                             const int* __restrict__ offs,
                                             const float* __restrict__ dinv,
                                             const float* __restrict__ b,
                                             float* __restrict__ H, int n,
                                             const float* __restrict__ w3,
                                             float* __restrict__ ts) {
    int wid = threadIdx.x >> 6;
    int lane = threadIdx.x & 63;
    int node = blockIdx.x * 4 + wid;
    if (node >= n) return;
    float d = dinv[node];
    float acc = Hs[(size_t)node * HID + lane];
    if (DEFER) acc *= d;
    int s = offs[node], e = offs[node + 1];
    int i = s;
    for (; i + 8 <= e; i += 8) {
        float part = 0.f;
#pragma unroll
        for (int k = 0; k < 8; k++) {
            int u = csr[i + k];
            float v = __builtin_nontemporal_load(Hs + (size_t)u * HID + lane);
            if (DEFER) v *= dinv[u];
            part += v;
        }
        acc += part;
    }
    for (; i < e; i++) {
        int u = csr[i];
        float v = __builtin_nontemporal_load(Hs + (size_t)u * HID + lane);
        if (DEFER) v *= dinv[u];
        acc += v;
    }
    float h = tanhf(acc * d + b[lane]);
    H[(size_t)node * HID + lane] = h;
    if (FUSE_TS) {
        float v = h * w3[lane];
        for (int o = 32; o > 0; o >>= 1) v += __shfl_down(v, o, 64);
        if (lane == 0) ts[node] = v * d;
    }
}

// -------- fused: layer-4 aggregate (own graph's nodes) + select + tail -------
__global__ __launch_bounds__(1024) void k_select_tail(
        const float* __restrict__ h1, const float* __restrict__ h2,
        const float* __restrict__ h3, const float* __restrict__ ts,
        const u16* __restrict__ csr, const int* __restrict__ offs,
        const float* __restrict__ dinv, const float* __restrict__ b3,
        const int* __restrict__ starts,
        const float* __restrict__ c1w, const float* __restrict__ c1b,
        const float* __restrict__ c2w, const float* __restrict__ c2b,
        const float* __restrict__ l1w, const float* __restrict__ l1b,
        const float* __restrict__ l2w, const float* __restrict__ l2b,
        float* __restrict__ out) {
    __shared__ float p[KTOP * LATENT];
    __shared__ float w1s[16 * LATENT];
    __shared__ float w2s[32 * 16 * 5];
    __shared__ float vv[2048];
    __shared__ int   pr[2048];
    __shared__ int   sel_s[KTOP];
    __shared__ float zpart[960];
    __shared__ float z1[16 * KTOP];
    __shared__ float z1p[16 * 15];
    __shared__ float flat[352];
    __shared__ float part[1024];
    __shared__ float y1[256];
    int g = blockIdx.x;
    int t = threadIdx.x;
    int s = starts[g];
    int c = starts[g + 1] - s;
    if (c > 2048) c = 2048;

    for (int i = t; i < 16 * LATENT; i += 1024) w1s[i] = c1w[i];
    for (int i = t; i < 32 * 16 * 5; i += 1024) w2s[i] = c2w[i];
    if (t < KTOP) sel_s[t] = -1;

    // ---- layer-4 aggregate for this graph's own (contiguous) nodes ----
    float bb = b3[0];
    for (int i = t; i < c; i += 1024) {
        int node = s + i;
        float acc = ts[node];
        int es = offs[node], ee = offs[node + 1];
        for (int j = es; j < ee; j++) acc += ts[csr[j]];
        vv[i] = tanhf(acc * dinv[node] + bb);
    }
    __syncthreads();

    // ---- select, 2-way j-split ----
    int chalf = c >> 1;
    for (int i2 = t; i2 < 2 * c; i2 += 1024) {
        int i = i2 >> 1, half = i2 & 1;
        float vi = vv[i];
        int j0 = half ? chalf : 0;
        int j1 = half ? c : chalf;
        int r = 0;
        for (int j = j0; j < j1; j++) {
            float vj = vv[j];
            r += (vj > vi) || (vj == vi && j < i);
        }
        pr[i2] = r;
    }
    __syncthreads();
    for (int i = t; i < c; i += 1024) {
        int r = pr[2 * i] + pr[2 * i + 1];
        if (r < KTOP) sel_s[r] = s + i;
    }
    __syncthreads();

    // ---- gather latent rows ----
    for (int i = t; i < KTOP * LATENT; i += 1024) {
        int slot = i / LATENT;
        int j = i - slot * LATENT;
        int node = sel_s[slot];
        float v = 0.f;
        if (node >= 0) {
            if (j < 64)       v = h1[(size_t)node * HID + j];
            else if (j < 128) v = h2[(size_t)node * HID + j - 64];
            else if (j < 192) v = h3[(size_t)node * HID + j - 128];
            else              v = vv[node - s];
        }
        p[i] = v;
    }
    __syncthreads();
    // conv1 193->16 + relu, 2-way K-split
    if (t < 960) {
        int to = (t < 480) ? t : t - 480;
        int half = (t < 480) ? 0 : 1;
        int ch = to / KTOP, tt = to - ch * KTOP;
        const float* wp = &w1s[ch * LATENT];
        const float* pp = &p[tt * LATENT];
        int j0 = half ? 96 : 0;
        int j1 = half ? LATENT : 96;
        float sa = 0.f;
        for (int j = j0; j < j1; j++) sa += pp[j] * wp[j];
        zpart[t] = sa;
    }
    __syncthreads();
    if (t < 480) {
        int ch = t / KTOP, tt = t - ch * KTOP;
        z1[ch * KTOP + tt] = fmaxf(zpart[t] + zpart[480 + t] + c1b[ch], 0.f);
    }
    __syncthreads();
    if (t < 16 * 15) {
        int ch = t / 15, tt = t - ch * 15;
        z1p[t] = fmaxf(z1[ch * KTOP + 2 * tt], z1[ch * KTOP + 2 * tt + 1]);
    }
    __syncthreads();
    if (t < 32 * 11) {
        int c2 = t / 11, tt = t - c2 * 11;
        float sa = c2b[c2];
        for (int c1i = 0; c1i < 16; c1i++) {
            const float* wp = &w2s[(c2 * 16 + c1i) * 5];
            const float* zp = &z1p[c1i * 15 + tt];
#pragma unroll
            for (int dt = 0; dt < 5; dt++) sa += zp[dt] * wp[dt];
        }
        flat[c2 * 11 + tt] = fmaxf(sa, 0.f);
    }
    __syncthreads();
    {
        int o = t & 255, ch = t >> 8;
        int i0 = ch * 88, i1 = i0 + 88;
        float sa = 0.f;
        for (int i = i0; i < i1; i++) sa += flat[i] * l1w[(size_t)i * 256 + o];
        part[t] = sa;
    }
    __syncthreads();
    if (t < 256)
        y1[t] = fmaxf(part[t] + part[256 + t] + part[512 + t] + part[768 + t] + l1b[t], 0.f);
    __syncthreads();
    if (t < 128) {
        int o = t >> 6, lane = t & 63;
        float sa = 0.f;
        for (int i = lane; i < 256; i += 64) sa += y1[i] * l2w[(size_t)i * 2 + o];
        for (int off = 32; off > 0; off >>= 1) sa += __shfl_down(sa, off, 64);
        if (lane == 0) out[g * 2 + o] = sa + l2b[o];
    }
}

// ---------------- launch ----------------
static inline char* align256(char* p) {
    return (char*)(((uintptr_t)p + 255) & ~(uintptr_t)255);
}

extern "C" void kernel_launch(void* const* d_in, const int* in_sizes, int n_in,
                              void* d_out, int out_size, void* d_ws, size_t ws_size,
                              hipStream_t stream) {
    const float* x     = (const float*)d_in[0];
    const int*  eidx   = (const int*)d_in[1];
    const int*  batch  = (const int*)d_in[2];
    const float* w0    = (const float*)d_in[3];
    const float* b0    = (const float*)d_in[4];
    const float* w1    = (const float*)d_in[5];
    const float* b1    = (const float*)d_in[6];
    const float* w2    = (const float*)d_in[7];
    const float* b2    = (const float*)d_in[8];
    const float* w3    = (const float*)d_in[9];
    const float* b3    = (const float*)d_in[10];
    const float* c1w   = (const float*)d_in[11];
    const float* c1b   = (const float*)d_in[12];
    const float* c2w   = (const float*)d_in[13];
    const float* c2b   = (const float*)d_in[14];
    const float* l1w   = (const float*)d_in[15];
    const float* l1b   = (const float*)d_in[16];
    const float* l2w   = (const float*)d_in[17];
    const float* l2b   = (const float*)d_in[18];

    int N = in_sizes[2];              // 50000 nodes
    int E = in_sizes[1] / 2;          // 800000 edges
    int K0 = in_sizes[0] / N;         // 128 input feats
    const int* esrc = eidx;
    const int* edst = eidx + E;

    char* w = (char*)d_ws;
    float* dinv  = (float*)w;             w = align256(w + (size_t)N * 4);
    int*   edeg  = (int*)w;               w = align256(w + (size_t)N * 4);
    int*   offs  = (int*)w;               w = align256(w + (size_t)(N + 1) * 4);
    int*   bsum  = (int*)w;               w = align256(w + 1024);
    float* ts    = (float*)w;             w = align256(w + (size_t)N * 4);
    int* starts  = (int*)w;               w = align256(w + (NGRAPH + 1) * 4);
    u16* rank    = (u16*)w;               w = align256(w + (size_t)E * 2);
    u16* csr     = (u16*)w;               w = align256(w + (size_t)E * 2);
    float* Hs    = (float*)w;             w = align256(w + (size_t)N * HID * 4);
    float* h1    = (float*)w;             w = align256(w + (size_t)N * HID * 4);
    float* h2    = (float*)w;             w = align256(w + (size_t)N * HID * 4);
    float* h3    = (float*)w;             w = align256(w + (size_t)N * HID * 4);

    int nb = (N + 255) / 256;             // 196
    int NG = (N + 63) / 64;               // 782
    int NH = (E + 1023) / 1024;           // 782 (4 edges per thread)
    int agg_grid = (N + 3) / 4;

    // zero degree array
    k_zero<<<nb, 256, 0, stream>>>(edeg, N);

    // K1: layer-1 GEMM (raw) || edge histogram+rank || graph starts
    int g1 = 2 * (NG > NH ? NG : NH);
    k_gemm_hist<<<g1, 256, 0, stream>>>(x, w0, Hs, N, K0, NG,
                                        edst, batch, edeg, rank, starts, E, N, NH);

    // CSR offsets + dinv
    k_scan1<<<nb, 256, 0, stream>>>(edeg, offs, bsum, dinv, N);
    k_scan23<<<nb, 256, 0, stream>>>(offs, bsum, N, E, nb);

    // CSR fill (no atomics)
    k_fill<<<(E / 4 + 255) / 256 + 1, 256, 0, stream>>>(esrc, edst, rank, offs, csr, E);

    // layer 1 aggregate (deferred dinv) -> h1
    k_agg<true, false><<<agg_grid, 256, 0, stream>>>(Hs, csr, offs, dinv, b0, h1, N, nullptr, nullptr);
    // layer 2
    k_gemm<<<NG, 256, 0, stream>>>(h1, w1, dinv, Hs, N, HID);
    k_agg<false, false><<<agg_grid, 256, 0, stream>>>(Hs, csr, offs, dinv, b1, h2, N, nullptr, nullptr);
    // layer 3 (+ fused layer-4 prescaled GEMV -> ts)
    k_gemm<<<NG, 256, 0, stream>>>(h2, w2, dinv, Hs, N, HID);
    k_agg<false, true><<<agg_grid, 256, 0, stream>>>(Hs, csr, offs, dinv, b2, h3, N, w3, ts);

    // fused layer-4 aggregate + top-30 select + tail
    k_select_tail<<<NGRAPH, 1024, 0, stream>>>(h1, h2, h3, ts, csr, offs, dinv, b3,
                                               starts,
                                               c1w, c1b, c2w, c2b,
                                               l1w, l1b, l2w, l2b,
                                               (float*)d_out);
}

// Round 13
// 249.755 us; speedup vs baseline: 1.3385x; 1.2164x over previous
//
#include <hip/hip_runtime.h>
#include <math.h>

#define NGRAPH 128
#define KTOP 30
#define LATENT 193
#define HID 64

typedef unsigned short u16;

// ---------------- zero edeg ----------------
__global__ void k_zero(int* edeg, int n) {
    int i = blockIdx.x * blockDim.x + threadIdx.x;
    if (i < n) edeg[i] = 0;
}

// ---------------- shared GEMM tile: 64x64 out, BK=32, k-major LDS ------------
template <bool SCALE>
__device__ __forceinline__ void gemm_tile(const float* __restrict__ A,
                                          const float* __restrict__ W,
                                          const float* __restrict__ dinv,
                                          float* __restrict__ Hs,
                                          int M, int K, int br,
                                          float (*As)[68], float (*Bs)[68]) {
    int tid = threadIdx.x;
    int tx = tid & 15, ty = tid >> 4;
    int kA = (tid & 7) * 4;
    int rA = tid >> 3;
    int kB = tid >> 3;
    int cB = (tid & 7) * 8;
    float c[4][4] = {};
    for (int k0 = 0; k0 < K; k0 += 32) {
#pragma unroll
        for (int it = 0; it < 2; ++it) {
            int row = it * 32 + rA;
            int grow = br + row;
            float4 v = make_float4(0.f, 0.f, 0.f, 0.f);
            if (grow < M) v = *(const float4*)(A + (size_t)grow * K + k0 + kA);
            As[kA + 0][row] = v.x;
            As[kA + 1][row] = v.y;
            As[kA + 2][row] = v.z;
            As[kA + 3][row] = v.w;
        }
        {
            const float* wp = W + (size_t)(k0 + kB) * 64 + cB;
            float4 v0 = *(const float4*)(wp);
            float4 v1 = *(const float4*)(wp + 4);
            *(float4*)&Bs[kB][cB] = v0;
            *(float4*)&Bs[kB][cB + 4] = v1;
        }
        __syncthreads();
#pragma unroll
        for (int kk = 0; kk < 32; ++kk) {
            float4 a4 = *(const float4*)&As[kk][ty * 4];
            float4 b4 = *(const float4*)&Bs[kk][tx * 4];
            c[0][0] += a4.x * b4.x; c[0][1] += a4.x * b4.y; c[0][2] += a4.x * b4.z; c[0][3] += a4.x * b4.w;
            c[1][0] += a4.y * b4.x; c[1][1] += a4.y * b4.y; c[1][2] += a4.y * b4.z; c[1][3] += a4.y * b4.w;
            c[2][0] += a4.z * b4.x; c[2][1] += a4.z * b4.y; c[2][2] += a4.z * b4.z; c[2][3] += a4.z * b4.w;
            c[3][0] += a4.w * b4.x; c[3][1] += a4.w * b4.y; c[3][2] += a4.w * b4.z; c[3][3] += a4.w * b4.w;
        }
        __syncthreads();
    }
#pragma unroll
    for (int i = 0; i < 4; i++) {
        int row = br + ty * 4 + i;
        if (row >= M) continue;
        float d = SCALE ? dinv[row] : 1.f;
        float4 o;
        o.x = c[i][0] * d; o.y = c[i][1] * d; o.z = c[i][2] * d; o.w = c[i][3] * d;
        *(float4*)(Hs + (size_t)row * HID + tx * 4) = o;
    }
}

// ---- K1: fused layer-1 GEMM (raw) + edge hist/rank (4 edges/thr) + starts ----
__global__ __launch_bounds__(256) void k_gemm_hist(
        const float* __restrict__ A, const float* __restrict__ W,
        float* __restrict__ Hs, int M, int K, int NG,
        const int* __restrict__ dst, const int* __restrict__ batch,
        int* edeg, u16* __restrict__ rank, int* starts,
        int E, int n, int NH) {
    __shared__ float As[32][68];
    __shared__ float Bs[32][68];
    int bid = blockIdx.x;
    if ((bid & 1) == 0) {
        int gid = bid >> 1;
        if (gid >= NG) return;
        gemm_tile<false>(A, W, nullptr, Hs, M, K, gid * 64, As, Bs);
    } else {
        int fid = bid >> 1;
        if (fid >= NH) return;
        int t = threadIdx.x;
        int gi = fid * 256 + t;
        if (gi < n) {
            int b = batch[gi];
            if (gi == 0) {
                for (int g = 0; g <= b; g++) starts[g] = 0;
            } else {
                int pb = batch[gi - 1];
                for (int g = pb + 1; g <= b; g++) starts[g] = gi;
            }
            if (gi == n - 1) {
                for (int g = b + 1; g <= NGRAPH; g++) starts[g] = n;
            }
        }
        int base = fid * 1024;
#pragma unroll
        for (int k = 0; k < 4; k++) {
            int e = base + k * 256 + t;
            if (e < E) {
                int d = dst[e];
                rank[e] = (u16)atomicAdd(&edeg[d], 1);
            }
        }
    }
}

// ---------------- scan stage 1 ----------------
__global__ void k_scan1(const int* __restrict__ edeg, int* offs, int* bsum,
                        float* dinv, int n) {
    __shared__ int s[256];
    int t = threadIdx.x;
    int gi = blockIdx.x * 256 + t;
    int v = (gi < n) ? edeg[gi] : 0;
    if (gi < n) dinv[gi] = rsqrtf((float)(v + 1));
    s[t] = v;
    __syncthreads();
    for (int o = 1; o < 256; o <<= 1) {
        int add = (t >= o) ? s[t - o] : 0;
        __syncthreads();
        s[t] += add;
        __syncthreads();
    }
    if (gi < n) offs[gi] = s[t] - v;
    if (t == 255) bsum[blockIdx.x] = s[255];
}

// ---------------- scan stage 2+3 fused ----------------
__global__ void k_scan23(int* offs, const int* __restrict__ bsum,
                         int n, int E, int nb) {
    __shared__ int s[256];
    int t = threadIdx.x;
    int bid = blockIdx.x;
    int v = (t < nb) ? bsum[t] : 0;
    s[t] = v;
    __syncthreads();
    for (int o = 1; o < 256; o <<= 1) {
        int add = (t >= o) ? s[t - o] : 0;
        __syncthreads();
        s[t] += add;
        __syncthreads();
    }
    int boffv = (bid == 0) ? 0 : s[bid - 1];
    int gi = bid * 256 + t;
    if (gi < n) offs[gi] += boffv;
    if (gi == 0) offs[n] = E;
}

// ---------------- CSR fill (no atomics) ----------------
__global__ __launch_bounds__(256) void k_fill(const int* __restrict__ src,
                                              const int* __restrict__ dst,
                                              const u16* __restrict__ rank,
                                              const int* __restrict__ offs,
                                              u16* __restrict__ csr, int E) {
    int t = blockIdx.x * 256 + threadIdx.x;
    int e0 = t * 4;
    if (e0 + 4 <= E) {
        int4 s4 = *(const int4*)(src + e0);
        int4 d4 = *(const int4*)(dst + e0);
        uint2 rv = *(const uint2*)(rank + e0);
        csr[offs[d4.x] + (rv.x & 0xffff)] = (u16)s4.x;
        csr[offs[d4.y] + (rv.x >> 16)]    = (u16)s4.y;
        csr[offs[d4.z] + (rv.y & 0xffff)] = (u16)s4.z;
        csr[offs[d4.w] + (rv.y >> 16)]    = (u16)s4.w;
    } else {
        for (int e = e0; e < E; e++)
            csr[offs[dst[e]] + rank[e]] = (u16)src[e];
    }
}

// ---------------- plain GEMM (layers 2,3): Hs = (A @ W) * dinv[row] ----------
__global__ __launch_bounds__(256) void k_gemm(const float* __restrict__ A,
                                              const float* __restrict__ W,
                                              const float* __restrict__ dinv,
                                              float* __restrict__ Hs,
                                              int M, int K) {
    __shared__ float As[32][68];
    __shared__ float Bs[32][68];
    gemm_tile<true>(A, W, dinv, Hs, M, K, blockIdx.x * 64, As, Bs);
}

// ------- aggregate (wave per node, R7-proven, plain loads) -------
template <bool DEFER, bool FUSE_TS>
__global__ __launch_bounds__(256) void k_agg(const float* __restrict__ Hs,
                                             const u16* __restrict__ csr,
                                             const int* __restrict__ offs,
                                             const float* __restrict__ dinv,
                                             const float* __restrict__ b,
                                             float* __restrict__ H, int n,
                                             const float* __restrict__ w3,
                                             float* __restrict__ ts) {
    int wid = threadIdx.x >> 6;
    int lane = threadIdx.x & 63;
    int node = blockIdx.x * 4 + wid;
    if (node >= n) return;
    float d = dinv[node];
    float acc = Hs[(size_t)node * HID + lane];
    if (DEFER) acc *= d;
    int s = offs[node], e = offs[node + 1];
    int i = s;
    for (; i + 8 <= e; i += 8) {
        float part = 0.f;
#pragma unroll
        for (int k = 0; k < 8; k++) {
            int u = csr[i + k];
            float v = Hs[(size_t)u * HID + lane];
            if (DEFER) v *= dinv[u];
            part += v;
        }
        acc += part;
    }
    for (; i < e; i++) {
        int u = csr[i];
        float v = Hs[(size_t)u * HID + lane];
        if (DEFER) v *= dinv[u];
        acc += v;
    }
    float h = tanhf(acc * d + b[lane]);
    H[(size_t)node * HID + lane] = h;
    if (FUSE_TS) {
        float v = h * w3[lane];
        for (int o = 32; o > 0; o >>= 1) v += __shfl_down(v, o, 64);
        if (lane == 0) ts[node] = v * d;
    }
}

// -------- fused: layer-4 aggregate (own graph's nodes) + select + tail -------
__global__ __launch_bounds__(1024) void k_select_tail(
        const float* __restrict__ h1, const float* __restrict__ h2,
        const float* __restrict__ h3, const float* __restrict__ ts,
        const u16* __restrict__ csr, const int* __restrict__ offs,
        const float* __restrict__ dinv, const float* __restrict__ b3,
        const int* __restrict__ starts,
        const float* __restrict__ c1w, const float* __restrict__ c1b,
        const float* __restrict__ c2w, const float* __restrict__ c2b,
        const float* __restrict__ l1w, const float* __restrict__ l1b,
        const float* __restrict__ l2w, const float* __restrict__ l2b,
        float* __restrict__ out) {
    __shared__ float p[KTOP * LATENT];
    __shared__ float w1s[16 * LATENT];
    __shared__ float w2s[32 * 16 * 5];
    __shared__ float vv[2048];
    __shared__ int   pr[2048];
    __shared__ int   sel_s[KTOP];
    __shared__ float zpart[960];
    __shared__ float z1[16 * KTOP];
    __shared__ float z1p[16 * 15];
    __shared__ float flat[352];
    __shared__ float part[1024];
    __shared__ float y1[256];
    int g = blockIdx.x;
    int t = threadIdx.x;
    int s = starts[g];
    int c = starts[g + 1] - s;
    if (c > 2048) c = 2048;

    for (int i = t; i < 16 * LATENT; i += 1024) w1s[i] = c1w[i];
    for (int i = t; i < 32 * 16 * 5; i += 1024) w2s[i] = c2w[i];
    if (t < KTOP) sel_s[t] = -1;

    // ---- layer-4 aggregate for this graph's own (contiguous) nodes ----
    float bb = b3[0];
    for (int i = t; i < c; i += 1024) {
        int node = s + i;
        float acc = ts[node];
        int es = offs[node], ee = offs[node + 1];
        for (int j = es; j < ee; j++) acc += ts[csr[j]];
        vv[i] = tanhf(acc * dinv[node] + bb);
    }
    __syncthreads();

    // ---- select, 2-way j-split ----
    int chalf = c >> 1;
    for (int i2 = t; i2 < 2 * c; i2 += 1024) {
        int i = i2 >> 1, half = i2 & 1;
        float vi = vv[i];
        int j0 = half ? chalf : 0;
        int j1 = half ? c : chalf;
        int r = 0;
        for (int j = j0; j < j1; j++) {
            float vj = vv[j];
            r += (vj > vi) || (vj == vi && j < i);
        }
        pr[i2] = r;
    }
    __syncthreads();
    for (int i = t; i < c; i += 1024) {
        int r = pr[2 * i] + pr[2 * i + 1];
        if (r < KTOP) sel_s[r] = s + i;
    }
    __syncthreads();

    // ---- gather latent rows ----
    for (int i = t; i < KTOP * LATENT; i += 1024) {
        int slot = i / LATENT;
        int j = i - slot * LATENT;
        int node = sel_s[slot];
        float v = 0.f;
        if (node >= 0) {
            if (j < 64)       v = h1[(size_t)node * HID + j];
            else if (j < 128) v = h2[(size_t)node * HID + j - 64];
            else if (j < 192) v = h3[(size_t)node * HID + j - 128];
            else              v = vv[node - s];
        }
        p[i] = v;
    }
    __syncthreads();
    // conv1 193->16 + relu, 2-way K-split
    if (t < 960) {
        int to = (t < 480) ? t : t - 480;
        int half = (t < 480) ? 0 : 1;
        int ch = to / KTOP, tt = to - ch * KTOP;
        const float* wp = &w1s[ch * LATENT];
        const float* pp = &p[tt * LATENT];
        int j0 = half ? 96 : 0;
        int j1 = half ? LATENT : 96;
        float sa = 0.f;
        for (int j = j0; j < j1; j++) sa += pp[j] * wp[j];
        zpart[t] = sa;
    }
    __syncthreads();
    if (t < 480) {
        int ch = t / KTOP, tt = t - ch * KTOP;
        z1[ch * KTOP + tt] = fmaxf(zpart[t] + zpart[480 + t] + c1b[ch], 0.f);
    }
    __syncthreads();
    if (t < 16 * 15) {
        int ch = t / 15, tt = t - ch * 15;
        z1p[t] = fmaxf(z1[ch * KTOP + 2 * tt], z1[ch * KTOP + 2 * tt + 1]);
    }
    __syncthreads();
    if (t < 32 * 11) {
        int c2 = t / 11, tt = t - c2 * 11;
        float sa = c2b[c2];
        for (int c1i = 0; c1i < 16; c1i++) {
            const float* wp = &w2s[(c2 * 16 + c1i) * 5];
            const float* zp = &z1p[c1i * 15 + tt];
#pragma unroll
            for (int dt = 0; dt < 5; dt++) sa += zp[dt] * wp[dt];
        }
        flat[c2 * 11 + tt] = fmaxf(sa, 0.f);
    }
    __syncthreads();
    {
        int o = t & 255, ch = t >> 8;
        int i0 = ch * 88, i1 = i0 + 88;
        float sa = 0.f;
        for (int i = i0; i < i1; i++) sa += flat[i] * l1w[(size_t)i * 256 + o];
        part[t] = sa;
    }
    __syncthreads();
    if (t < 256)
        y1[t] = fmaxf(part[t] + part[256 + t] + part[512 + t] + part[768 + t] + l1b[t], 0.f);
    __syncthreads();
    if (t < 128) {
        int o = t >> 6, lane = t & 63;
        float sa = 0.f;
        for (int i = lane; i < 256; i += 64) sa += y1[i] * l2w[(size_t)i * 2 + o];
        for (int off = 32; off > 0; off >>= 1) sa += __shfl_down(sa, off, 64);
        if (lane == 0) out[g * 2 + o] = sa + l2b[o];
    }
}

// ---------------- launch ----------------
static inline char* align256(char* p) {
    return (char*)(((uintptr_t)p + 255) & ~(uintptr_t)255);
}

extern "C" void kernel_launch(void* const* d_in, const int* in_sizes, int n_in,
                              void* d_out, int out_size, void* d_ws, size_t ws_size,
                              hipStream_t stream) {
    const float* x     = (const float*)d_in[0];
    const int*  eidx   = (const int*)d_in[1];
    const int*  batch  = (const int*)d_in[2];
    const float* w0    = (const float*)d_in[3];
    const float* b0    = (const float*)d_in[4];
    const float* w1    = (const float*)d_in[5];
    const float* b1    = (const float*)d_in[6];
    const float* w2    = (const float*)d_in[7];
    const float* b2    = (const float*)d_in[8];
    const float* w3    = (const float*)d_in[9];
    const float* b3    = (const float*)d_in[10];
    const float* c1w   = (const float*)d_in[11];
    const float* c1b   = (const float*)d_in[12];
    const float* c2w   = (const float*)d_in[13];
    const float* c2b   = (const float*)d_in[14];
    const float* l1w   = (const float*)d_in[15];
    const float* l1b   = (const float*)d_in[16];
    const float* l2w   = (const float*)d_in[17];
    const float* l2b   = (const float*)d_in[18];

    int N = in_sizes[2];              // 50000 nodes
    int E = in_sizes[1] / 2;          // 800000 edges
    int K0 = in_sizes[0] / N;         // 128 input feats
    const int* esrc = eidx;
    const int* edst = eidx + E;

    char* w = (char*)d_ws;
    float* dinv  = (float*)w;             w = align256(w + (size_t)N * 4);
    int*   edeg  = (int*)w;               w = align256(w + (size_t)N * 4);
    int*   offs  = (int*)w;               w = align256(w + (size_t)(N + 1) * 4);
    int*   bsum  = (int*)w;               w = align256(w + 1024);
    float* ts    = (float*)w;             w = align256(w + (size_t)N * 4);
    int* starts  = (int*)w;               w = align256(w + (NGRAPH + 1) * 4);
    u16* rank    = (u16*)w;               w = align256(w + (size_t)E * 2);
    u16* csr     = (u16*)w;               w = align256(w + (size_t)E * 2);
    float* Hs    = (float*)w;             w = align256(w + (size_t)N * HID * 4);
    float* h1    = (float*)w;             w = align256(w + (size_t)N * HID * 4);
    float* h2    = (float*)w;             w = align256(w + (size_t)N * HID * 4);
    float* h3    = (float*)w;             w = align256(w + (size_t)N * HID * 4);

    int nb = (N + 255) / 256;             // 196
    int NG = (N + 63) / 64;               // 782
    int NH = (E + 1023) / 1024;           // 782 (4 edges per thread)
    int agg_grid = (N + 3) / 4;

    // zero degree array
    k_zero<<<nb, 256, 0, stream>>>(edeg, N);

    // K1: layer-1 GEMM (raw) || edge histogram+rank || graph starts
    int g1 = 2 * (NG > NH ? NG : NH);
    k_gemm_hist<<<g1, 256, 0, stream>>>(x, w0, Hs, N, K0, NG,
                                        edst, batch, edeg, rank, starts, E, N, NH);

    // CSR offsets + dinv
    k_scan1<<<nb, 256, 0, stream>>>(edeg, offs, bsum, dinv, N);
    k_scan23<<<nb, 256, 0, stream>>>(offs, bsum, N, E, nb);

    // CSR fill (no atomics)
    k_fill<<<(E / 4 + 255) / 256 + 1, 256, 0, stream>>>(esrc, edst, rank, offs, csr, E);

    // layer 1 aggregate (deferred dinv) -> h1
    k_agg<true, false><<<agg_grid, 256, 0, stream>>>(Hs, csr, offs, dinv, b0, h1, N, nullptr, nullptr);
    // layer 2
    k_gemm<<<NG, 256, 0, stream>>>(h1, w1, dinv, Hs, N, HID);
    k_agg<false, false><<<agg_grid, 256, 0, stream>>>(Hs, csr, offs, dinv, b1, h2, N, nullptr, nullptr);
    // layer 3 (+ fused layer-4 prescaled GEMV -> ts)
    k_gemm<<<NG, 256, 0, stream>>>(h2, w2, dinv, Hs, N, HID);
    k_agg<false, true><<<agg_grid, 256, 0, stream>>>(Hs, csr, offs, dinv, b2, h3, N, w3, ts);

    // fused layer-4 aggregate + top-30 select + tail
    k_select_tail<<<NGRAPH, 1024, 0, stream>>>(h1, h2, h3, ts, csr, offs, dinv, b3,
                                               starts,
                                               c1w, c1b, c2w, c2b,
                                               l1w, l1b, l2w, l2b,
                                               (float*)d_out);
}